// Round 1
// baseline (7726.993 us; speedup 1.0000x reference)
//
#include <hip/hip_runtime.h>
#include <math.h>

// ---------------- problem constants ----------------
constexpr int B  = 2;
constexpr int S  = 4096;
constexpr int H  = 768;
constexpr int NH = 12;
constexpr int FF = 3072;
constexpr int L  = 4;
constexpr int BLK = 64;
constexpr int R  = 3;
constexpr int NB = S / BLK;   // 64
constexpr int D  = H / NH;    // 64
constexpr int AB = 8;         // attended blocks: 3 window + 2 global + 3 random
constexpr float SCALE = 0.125f;  // 1/sqrt(64)

constexpr int ROWS = B * S;          // 8192
constexpr size_t XSZ = (size_t)B * S * H;   // 6291456

// ---------------- embedding: x = ids @ emb_w + emb_b ----------------
__global__ __launch_bounds__(256) void embed_kernel(
    const float* __restrict__ ids, const float* __restrict__ w,
    const float* __restrict__ bvec, float* __restrict__ x) {
  int i = blockIdx.x * 256 + threadIdx.x;
  if (i >= (int)XSZ) return;
  int hc = i % H;
  int bs = i / H;
  float s = bvec[hc];
  #pragma unroll
  for (int j = 0; j < 4; ++j) s += ids[bs * 4 + j] * w[j * H + hc];
  x[i] = s;
}

// ---------------- layernorm (biased var, eps=1e-12) ----------------
__global__ __launch_bounds__(256) void ln_kernel(
    const float* __restrict__ x, const float* __restrict__ g,
    const float* __restrict__ bvec, float* __restrict__ out) {
  int row = blockIdx.x;
  const float* xr = x + (size_t)row * H;
  int t = threadIdx.x;
  float v0 = xr[t], v1 = xr[t + 256], v2 = xr[t + 512];
  float s  = v0 + v1 + v2;
  float ss = v0 * v0 + v1 * v1 + v2 * v2;
  for (int off = 1; off < 64; off <<= 1) {
    s  += __shfl_xor(s,  off);
    ss += __shfl_xor(ss, off);
  }
  __shared__ float sm[8];
  int w = t >> 6, lane = t & 63;
  if (lane == 0) { sm[w] = s; sm[4 + w] = ss; }
  __syncthreads();
  s  = sm[0] + sm[1] + sm[2] + sm[3];
  ss = sm[4] + sm[5] + sm[6] + sm[7];
  float mean = s * (1.0f / H);
  float var  = ss * (1.0f / H) - mean * mean;
  float rstd = rsqrtf(var + 1e-12f);
  float* orow = out + (size_t)row * H;
  orow[t]       = (v0 - mean) * rstd * g[t]       + bvec[t];
  orow[t + 256] = (v1 - mean) * rstd * g[t + 256] + bvec[t + 256];
  orow[t + 512] = (v2 - mean) * rstd * g[t + 512] + bvec[t + 512];
}

// ---------------- tiled fp32 GEMM: C = A[M,K] @ W[K,N] + bias (+epilogue) ----
// EPI: 0 = bias only, 1 = bias + residual add, 2 = bias + exact gelu
template <int EPI>
__global__ __launch_bounds__(256) void gemm_kernel(
    const float* __restrict__ Amat, const float* __restrict__ Wmat,
    const float* __restrict__ bias, const float* __restrict__ res,
    float* __restrict__ C, int M, int N, int K) {
  __shared__ float As[16][68];  // [k][m], pad -> 272B row stride (16B aligned)
  __shared__ float Bs[16][68];  // [k][n]
  const int t  = threadIdx.x;
  const int ty = t >> 4, tx = t & 15;
  const int bm = blockIdx.y * 64, bn = blockIdx.x * 64;
  float acc[4][4] = {};
  for (int k0 = 0; k0 < K; k0 += 16) {
    #pragma unroll
    for (int i = 0; i < 4; ++i) {
      int li = t + i * 256;
      int m = li >> 4, kk = li & 15;
      As[kk][m] = Amat[(size_t)(bm + m) * K + k0 + kk];
    }
    #pragma unroll
    for (int i = 0; i < 4; ++i) {
      int li = t + i * 256;
      int kk = li >> 6, n = li & 63;
      Bs[kk][n] = Wmat[(size_t)(k0 + kk) * N + bn + n];
    }
    __syncthreads();
    #pragma unroll
    for (int kk = 0; kk < 16; ++kk) {
      float av[4], bv[4];
      #pragma unroll
      for (int i = 0; i < 4; ++i) av[i] = As[kk][ty * 4 + i];
      #pragma unroll
      for (int j = 0; j < 4; ++j) bv[j] = Bs[kk][tx * 4 + j];
      #pragma unroll
      for (int i = 0; i < 4; ++i)
        #pragma unroll
        for (int j = 0; j < 4; ++j) acc[i][j] += av[i] * bv[j];
    }
    __syncthreads();
  }
  #pragma unroll
  for (int i = 0; i < 4; ++i) {
    int m = bm + ty * 4 + i;
    #pragma unroll
    for (int j = 0; j < 4; ++j) {
      int n = bn + tx * 4 + j;
      float val = acc[i][j] + bias[n];
      if (EPI == 1) val += res[(size_t)m * N + n];
      if (EPI == 2) val = 0.5f * val * (1.0f + erff(val * 0.70710678118654752f));
      C[(size_t)m * N + n] = val;
    }
  }
}

// ---------------- BigBird sparse attention (flash-style, per q-block) -------
__global__ __launch_bounds__(256) void attn_kernel(
    const float* __restrict__ q, const float* __restrict__ k,
    const float* __restrict__ v, const int* __restrict__ rb,
    float* __restrict__ ao) {
  __shared__ float Qs[64][65];
  __shared__ float Ks[64][65];  // reused as P after scores consumed
  __shared__ float Vs[64][65];
  const int n = blockIdx.x, hh = blockIdx.y, b = blockIdx.z;
  const int t = threadIdx.x;
  const int ty = t >> 4, tx = t & 15;

  #pragma unroll
  for (int i = 0; i < 16; ++i) {
    int li = t + i * 256;
    int r = li >> 6, d = li & 63;
    Qs[r][d] = q[((size_t)(b * S + n * 64 + r)) * H + hh * 64 + d];
  }
  float acc[4][4] = {};
  float mrow[4], lrow[4];
  #pragma unroll
  for (int i = 0; i < 4; ++i) { mrow[i] = -1e30f; lrow[i] = 0.f; }
  __syncthreads();

  for (int a = 0; a < AB; ++a) {
    int kb;
    if      (a == 0) kb = (n > 0) ? n - 1 : 0;
    else if (a == 1) kb = n;
    else if (a == 2) kb = (n < NB - 1) ? n + 1 : NB - 1;
    else if (a == 3) kb = 0;
    else if (a == 4) kb = NB - 1;
    else             kb = rb[n * R + (a - 5)];

    #pragma unroll
    for (int i = 0; i < 16; ++i) {
      int li = t + i * 256;
      int c = li >> 6, d = li & 63;
      size_t g = ((size_t)(b * S + kb * 64 + c)) * H + hh * 64 + d;
      Ks[c][d] = k[g];
      Vs[c][d] = v[g];
    }
    __syncthreads();

    float s[4][4] = {};
    for (int d0 = 0; d0 < 64; ++d0) {
      float av[4], bv[4];
      #pragma unroll
      for (int i = 0; i < 4; ++i) av[i] = Qs[ty * 4 + i][d0];
      #pragma unroll
      for (int j = 0; j < 4; ++j) bv[j] = Ks[tx * 4 + j][d0];
      #pragma unroll
      for (int i = 0; i < 4; ++i)
        #pragma unroll
        for (int j = 0; j < 4; ++j) s[i][j] += av[i] * bv[j];
    }
    // online softmax update (per row, reduce across the 16 tx lanes)
    #pragma unroll
    for (int i = 0; i < 4; ++i) {
      float rm = -1e30f;
      #pragma unroll
      for (int j = 0; j < 4; ++j) { s[i][j] *= SCALE; rm = fmaxf(rm, s[i][j]); }
      for (int off = 1; off < 16; off <<= 1) rm = fmaxf(rm, __shfl_xor(rm, off));
      float mn = fmaxf(mrow[i], rm);
      float corr = __expf(mrow[i] - mn);
      mrow[i] = mn;
      float rs = 0.f;
      #pragma unroll
      for (int j = 0; j < 4; ++j) { s[i][j] = __expf(s[i][j] - mn); rs += s[i][j]; }
      for (int off = 1; off < 16; off <<= 1) rs += __shfl_xor(rs, off);
      lrow[i] = lrow[i] * corr + rs;
      #pragma unroll
      for (int j = 0; j < 4; ++j) acc[i][j] *= corr;
    }
    __syncthreads();  // everyone done reading Ks (scores)
    #pragma unroll
    for (int i = 0; i < 4; ++i)
      #pragma unroll
      for (int j = 0; j < 4; ++j) Ks[ty * 4 + i][tx * 4 + j] = s[i][j];
    __syncthreads();
    // O += P @ V
    for (int kk = 0; kk < 64; ++kk) {
      float av[4], bv[4];
      #pragma unroll
      for (int i = 0; i < 4; ++i) av[i] = Ks[ty * 4 + i][kk];
      #pragma unroll
      for (int j = 0; j < 4; ++j) bv[j] = Vs[kk][tx * 4 + j];
      #pragma unroll
      for (int i = 0; i < 4; ++i)
        #pragma unroll
        for (int j = 0; j < 4; ++j) acc[i][j] += av[i] * bv[j];
    }
    __syncthreads();  // before restaging K/V
  }

  #pragma unroll
  for (int i = 0; i < 4; ++i) {
    float inv = 1.0f / lrow[i];
    #pragma unroll
    for (int j = 0; j < 4; ++j)
      ao[((size_t)(b * S + n * 64 + ty * 4 + i)) * H + hh * 64 + tx * 4 + j] =
          acc[i][j] * inv;
  }
}

// ---------------- classifier: softmax(x @ clf_w + clf_b) --------------------
__global__ __launch_bounds__(64) void clf_kernel(
    const float* __restrict__ x, const float* __restrict__ w,
    const float* __restrict__ bvec, float* __restrict__ out) {
  int row = blockIdx.x;
  int lane = threadIdx.x;
  const float* xr = x + (size_t)row * H;
  float p0 = 0.f, p1 = 0.f, p2 = 0.f, p3 = 0.f;
  for (int d = lane; d < H; d += 64) {
    float xv = xr[d];
    p0 += xv * w[d * 4 + 0];
    p1 += xv * w[d * 4 + 1];
    p2 += xv * w[d * 4 + 2];
    p3 += xv * w[d * 4 + 3];
  }
  for (int off = 1; off < 64; off <<= 1) {
    p0 += __shfl_xor(p0, off);
    p1 += __shfl_xor(p1, off);
    p2 += __shfl_xor(p2, off);
    p3 += __shfl_xor(p3, off);
  }
  if (lane == 0) {
    float l0 = p0 + bvec[0], l1 = p1 + bvec[1], l2 = p2 + bvec[2], l3 = p3 + bvec[3];
    float mx = fmaxf(fmaxf(l0, l1), fmaxf(l2, l3));
    float e0 = __expf(l0 - mx), e1 = __expf(l1 - mx), e2 = __expf(l2 - mx), e3 = __expf(l3 - mx);
    float inv = 1.0f / (e0 + e1 + e2 + e3);
    out[row * 4 + 0] = e0 * inv;
    out[row * 4 + 1] = e1 * inv;
    out[row * 4 + 2] = e2 * inv;
    out[row * 4 + 3] = e3 * inv;
  }
}

// ---------------- driver ----------------------------------------------------
extern "C" void kernel_launch(void* const* d_in, const int* in_sizes, int n_in,
                              void* d_out, int out_size, void* d_ws, size_t ws_size,
                              hipStream_t stream) {
  const float* input_ids = (const float*)d_in[0];
  const int*   rand_bl   = (const int*)  d_in[1];
  const float* emb_w = (const float*)d_in[2];
  const float* emb_b = (const float*)d_in[3];
  const float* ln1_g = (const float*)d_in[4];
  const float* ln1_b = (const float*)d_in[5];
  const float* wq = (const float*)d_in[6];
  const float* bq = (const float*)d_in[7];
  const float* wk = (const float*)d_in[8];
  const float* bk = (const float*)d_in[9];
  const float* wv = (const float*)d_in[10];
  const float* bv = (const float*)d_in[11];
  const float* wo = (const float*)d_in[12];
  const float* bo = (const float*)d_in[13];
  const float* ln2_g = (const float*)d_in[14];
  const float* ln2_b = (const float*)d_in[15];
  const float* w1 = (const float*)d_in[16];
  const float* b1 = (const float*)d_in[17];
  const float* w2 = (const float*)d_in[18];
  const float* b2 = (const float*)d_in[19];
  const float* clf_w = (const float*)d_in[20];
  const float* clf_b = (const float*)d_in[21];

  float* ws = (float*)d_ws;
  float* x  = ws;
  float* h  = ws + XSZ;
  float* q  = ws + 2 * XSZ;
  float* k  = ws + 3 * XSZ;
  float* v  = ws + 4 * XSZ;
  float* ao = ws + 5 * XSZ;
  float* ff = q;  // FFN intermediate [B*S, FF] aliases q..ao (dead by then)

  embed_kernel<<<(int)((XSZ + 255) / 256), 256, 0, stream>>>(input_ids, emb_w, emb_b, x);

  for (int l = 0; l < L; ++l) {
    const size_t oHH = (size_t)l * H * H;
    ln_kernel<<<ROWS, 256, 0, stream>>>(x, ln1_g + l * H, ln1_b + l * H, h);

    gemm_kernel<0><<<dim3(H / 64, ROWS / 64), 256, 0, stream>>>(
        h, wq + oHH, bq + l * H, nullptr, q, ROWS, H, H);
    gemm_kernel<0><<<dim3(H / 64, ROWS / 64), 256, 0, stream>>>(
        h, wk + oHH, bk + l * H, nullptr, k, ROWS, H, H);
    gemm_kernel<0><<<dim3(H / 64, ROWS / 64), 256, 0, stream>>>(
        h, wv + oHH, bv + l * H, nullptr, v, ROWS, H, H);

    attn_kernel<<<dim3(NB, NH, B), 256, 0, stream>>>(q, k, v, rand_bl, ao);

    gemm_kernel<1><<<dim3(H / 64, ROWS / 64), 256, 0, stream>>>(
        ao, wo + oHH, bo + l * H, x, x, ROWS, H, H);

    ln_kernel<<<ROWS, 256, 0, stream>>>(x, ln2_g + l * H, ln2_b + l * H, h);

    gemm_kernel<2><<<dim3(FF / 64, ROWS / 64), 256, 0, stream>>>(
        h, w1 + (size_t)l * H * FF, b1 + l * FF, nullptr, ff, ROWS, FF, H);
    gemm_kernel<1><<<dim3(H / 64, ROWS / 64), 256, 0, stream>>>(
        ff, w2 + (size_t)l * FF * H, b2 + l * H, x, x, ROWS, H, FF);
  }

  clf_kernel<<<ROWS, 64, 0, stream>>>(x, clf_w, clf_b, (float*)d_out);
}

// Round 2
// 1287.694 us; speedup vs baseline: 6.0006x; 6.0006x over previous
//
#include <hip/hip_runtime.h>
#include <math.h>

// ---------------- problem constants ----------------
constexpr int B  = 2;
constexpr int S  = 4096;
constexpr int H  = 768;
constexpr int NH = 12;
constexpr int FF = 3072;
constexpr int L  = 4;
constexpr int R  = 3;
constexpr int NB = 64;
constexpr int AB = 8;            // 3 window + 2 global + 3 random
constexpr float SCALE = 0.125f;  // 1/sqrt(64)
constexpr int QKV_N = 3 * H;     // 2304

constexpr int ROWS = B * S;                  // 8192
constexpr size_t XSZ = (size_t)B * S * H;    // 6291456

typedef short bf16x8 __attribute__((ext_vector_type(8)));
typedef unsigned short u16x8 __attribute__((ext_vector_type(8)));
typedef float f32x4 __attribute__((ext_vector_type(4)));
typedef unsigned short ushort_t;

// fp32 -> bf16 round-nearest-even
__device__ __forceinline__ ushort_t f2b(float f) {
  union { float f; unsigned u; } c; c.f = f;
  unsigned r = c.u + 0x7fffu + ((c.u >> 16) & 1u);
  return (ushort_t)(r >> 16);
}

__device__ __forceinline__ void gload16(const void* g, void* l) {
  __builtin_amdgcn_global_load_lds(
      (const __attribute__((address_space(1))) unsigned int*)g,
      (__attribute__((address_space(3))) unsigned int*)l, 16, 0, 0);
}

// ---------------- embedding: x = ids @ emb_w + emb_b (fp32 out) -------------
__global__ __launch_bounds__(256) void embed_kernel(
    const float* __restrict__ ids, const float* __restrict__ w,
    const float* __restrict__ bvec, float* __restrict__ x) {
  int i = blockIdx.x * 256 + threadIdx.x;
  if (i >= (int)XSZ) return;
  int hc = i % H;
  int bs = i / H;
  float s = bvec[hc];
  #pragma unroll
  for (int j = 0; j < 4; ++j) s += ids[bs * 4 + j] * w[j * H + hc];
  x[i] = s;
}

// ---------------- layernorm: fp32 in -> bf16 out ----------------------------
__global__ __launch_bounds__(256) void ln_kernel(
    const float* __restrict__ x, const float* __restrict__ g,
    const float* __restrict__ bvec, ushort_t* __restrict__ out) {
  int row = blockIdx.x;
  const float* xr = x + (size_t)row * H;
  int t = threadIdx.x;
  float v0 = xr[t], v1 = xr[t + 256], v2 = xr[t + 512];
  float s  = v0 + v1 + v2;
  float ss = v0 * v0 + v1 * v1 + v2 * v2;
  for (int off = 1; off < 64; off <<= 1) {
    s  += __shfl_xor(s,  off);
    ss += __shfl_xor(ss, off);
  }
  __shared__ float sm[8];
  int w = t >> 6, lane = t & 63;
  if (lane == 0) { sm[w] = s; sm[4 + w] = ss; }
  __syncthreads();
  s  = sm[0] + sm[1] + sm[2] + sm[3];
  ss = sm[4] + sm[5] + sm[6] + sm[7];
  float mean = s * (1.0f / H);
  float var  = ss * (1.0f / H) - mean * mean;
  float rstd = rsqrtf(var + 1e-12f);
  ushort_t* orow = out + (size_t)row * H;
  orow[t]       = f2b((v0 - mean) * rstd * g[t]       + bvec[t]);
  orow[t + 256] = f2b((v1 - mean) * rstd * g[t + 256] + bvec[t + 256]);
  orow[t + 512] = f2b((v2 - mean) * rstd * g[t + 512] + bvec[t + 512]);
}

// ---------------- weight transpose + fp32->bf16: out[n*K+k] = in[k*N+n] -----
__global__ __launch_bounds__(256) void tcvt_kernel(
    const float* __restrict__ in, ushort_t* __restrict__ out,
    int K, int N, size_t inZ, size_t outZ) {
  __shared__ float tile[32][33];
  const float* inz = in + blockIdx.z * inZ;
  ushort_t* outz = out + blockIdx.z * outZ;
  int k0 = blockIdx.y * 32, n0 = blockIdx.x * 32;
  int tx = threadIdx.x & 31, ty = threadIdx.x >> 5;  // 32 x 8
  #pragma unroll
  for (int i = 0; i < 4; ++i) {
    int kk = ty + i * 8;
    tile[kk][tx] = inz[(size_t)(k0 + kk) * N + n0 + tx];
  }
  __syncthreads();
  #pragma unroll
  for (int i = 0; i < 4; ++i) {
    int nn = ty + i * 8;
    outz[(size_t)(n0 + nn) * K + k0 + tx] = f2b(tile[tx][nn]);
  }
}

// ---------------- concat q/k/v biases: [L][2304] ----------------------------
__global__ __launch_bounds__(256) void concat_bias_kernel(
    const float* __restrict__ bq, const float* __restrict__ bk,
    const float* __restrict__ bv, float* __restrict__ out) {
  int i = blockIdx.x * 256 + threadIdx.x;
  if (i >= L * QKV_N) return;
  int l = i / QKV_N, c = i % QKV_N;
  float val = (c < H) ? bq[l * H + c] : (c < 2 * H) ? bk[l * H + c - H] : bv[l * H + c - 2 * H];
  out[i] = val;
}

// ---------------- bf16 MFMA GEMM: C = A[M,K] @ Wt[N,K]^T + bias -------------
// EPI: 0 = bias -> bf16 out, 1 = bias + residual -> fp32 out, 2 = bias + gelu -> bf16 out
template <int EPI>
__global__ __launch_bounds__(256) void bgemm(
    const ushort_t* __restrict__ A, const ushort_t* __restrict__ Wt,
    const float* __restrict__ bias, const float* __restrict__ res,
    float* __restrict__ Cf, ushort_t* __restrict__ Cb,
    int M, int N, int K) {
  __shared__ ushort_t As[128 * 32];  // [row][k] 64B rows
  __shared__ ushort_t Bs[128 * 32];  // [n][k]
  const int t = threadIdx.x;
  const int wid = t >> 6, lane = t & 63;
  const int fcol = lane & 15, fgrp = lane >> 4;
  const int wr = wid >> 1, wc = wid & 1;
  const int bm = blockIdx.y * 128, bn = blockIdx.x * 128;

  f32x4 acc[4][4] = {};

  const int srow = wid * 32 + (lane >> 2);   // staged row (+16 per i)
  const int sko  = (lane & 3) * 8;
  const ushort_t* Ag = A  + (size_t)(bm + srow) * K + sko;
  const ushort_t* Bg = Wt + (size_t)(bn + srow) * K + sko;

  for (int k0 = 0; k0 < K; k0 += 32) {
    #pragma unroll
    for (int i = 0; i < 2; ++i) {
      gload16(Ag + (size_t)i * 16 * K + k0, &As[(wid * 2 + i) * 512]);
      gload16(Bg + (size_t)i * 16 * K + k0, &Bs[(wid * 2 + i) * 512]);
    }
    __syncthreads();
    bf16x8 af[4], bf[4];
    #pragma unroll
    for (int mi = 0; mi < 4; ++mi)
      af[mi] = *(const bf16x8*)&As[(wr * 64 + mi * 16 + fcol) * 32 + fgrp * 8];
    #pragma unroll
    for (int ni = 0; ni < 4; ++ni)
      bf[ni] = *(const bf16x8*)&Bs[(wc * 64 + ni * 16 + fcol) * 32 + fgrp * 8];
    #pragma unroll
    for (int mi = 0; mi < 4; ++mi)
      #pragma unroll
      for (int ni = 0; ni < 4; ++ni)
        acc[mi][ni] = __builtin_amdgcn_mfma_f32_16x16x32_bf16(af[mi], bf[ni], acc[mi][ni], 0, 0, 0);
    __syncthreads();
  }

  #pragma unroll
  for (int mi = 0; mi < 4; ++mi) {
    #pragma unroll
    for (int ni = 0; ni < 4; ++ni) {
      int n = bn + wc * 64 + ni * 16 + fcol;
      float bb = bias[n];
      #pragma unroll
      for (int r = 0; r < 4; ++r) {
        int m = bm + wr * 64 + mi * 16 + fgrp * 4 + r;
        float val = acc[mi][ni][r] + bb;
        if (EPI == 1) {
          Cf[(size_t)m * N + n] = val + res[(size_t)m * N + n];
        } else if (EPI == 2) {
          val = 0.5f * val * (1.0f + erff(val * 0.70710678118654752f));
          Cb[(size_t)m * N + n] = f2b(val);
        } else {
          Cb[(size_t)m * N + n] = f2b(val);
        }
      }
    }
  }
}

// ---------------- BigBird sparse attention, bf16 MFMA flash-style -----------
// qkv: [ROWS][2304] bf16 (q | k | v). ao: [ROWS][768] bf16.
__global__ __launch_bounds__(256) void attn_mfma(
    const ushort_t* __restrict__ qkv, const int* __restrict__ rb,
    ushort_t* __restrict__ ao) {
  __shared__ ushort_t Ks[64 * 72];     // [kpos][d], 144B rows
  __shared__ ushort_t Vt[64 * 72];     // [d][kpos]
  __shared__ ushort_t Ps[4][16 * 72];  // per-wave P [q][kpos]
  const int n = blockIdx.x, hh = blockIdx.y, b = blockIdx.z;
  const int t = threadIdx.x;
  const int wid = t >> 6, lane = t & 63;
  const int fcol = lane & 15, fgrp = lane >> 4;
  const int qr0 = n * 64 + wid * 16;

  // Q fragments in registers (rows qr0..qr0+15)
  bf16x8 qf[2];
  #pragma unroll
  for (int kc = 0; kc < 2; ++kc)
    qf[kc] = *(const bf16x8*)&qkv[((size_t)(b * S) + qr0 + fcol) * QKV_N + hh * 64 + kc * 32 + fgrp * 8];

  f32x4 oacc[4] = {};
  float mrow[4], lrow[4];
  #pragma unroll
  for (int r = 0; r < 4; ++r) { mrow[r] = -1e30f; lrow[r] = 0.f; }

  const int skp = t >> 3;        // staged kpos (+32 per i)
  const int sdo = (t & 7) * 8;   // staged d offset

  for (int a = 0; a < AB; ++a) {
    int kb;
    if      (a == 0) kb = (n > 0) ? n - 1 : 0;
    else if (a == 1) kb = n;
    else if (a == 2) kb = (n < NB - 1) ? n + 1 : NB - 1;
    else if (a == 3) kb = 0;
    else if (a == 4) kb = NB - 1;
    else             kb = rb[n * R + (a - 5)];

    const ushort_t* kbase = qkv + ((size_t)(b * S) + kb * 64) * QKV_N + H + hh * 64;
    const ushort_t* vbase = qkv + ((size_t)(b * S) + kb * 64) * QKV_N + 2 * H + hh * 64;
    #pragma unroll
    for (int i = 0; i < 2; ++i) {
      int kp = skp + i * 32;
      u16x8 kv = *(const u16x8*)&kbase[(size_t)kp * QKV_N + sdo];
      *(u16x8*)&Ks[kp * 72 + sdo] = kv;
      u16x8 vv = *(const u16x8*)&vbase[(size_t)kp * QKV_N + sdo];
      #pragma unroll
      for (int j = 0; j < 8; ++j) Vt[(sdo + j) * 72 + kp] = vv[j];
    }
    __syncthreads();

    // S = Q K^T  (rows q, cols kpos)
    f32x4 sacc[4] = {};
    #pragma unroll
    for (int ni = 0; ni < 4; ++ni)
      #pragma unroll
      for (int kc = 0; kc < 2; ++kc) {
        bf16x8 kf = *(const bf16x8*)&Ks[(ni * 16 + fcol) * 72 + kc * 32 + fgrp * 8];
        sacc[ni] = __builtin_amdgcn_mfma_f32_16x16x32_bf16(qf[kc], kf, sacc[ni], 0, 0, 0);
      }

    // online softmax (each lane owns rows fgrp*4+r, cols spread over lanes 0-15)
    #pragma unroll
    for (int ni = 0; ni < 4; ++ni)
      #pragma unroll
      for (int r = 0; r < 4; ++r) sacc[ni][r] *= SCALE;
    #pragma unroll
    for (int r = 0; r < 4; ++r) {
      float tm = fmaxf(fmaxf(sacc[0][r], sacc[1][r]), fmaxf(sacc[2][r], sacc[3][r]));
      tm = fmaxf(tm, __shfl_xor(tm, 1));
      tm = fmaxf(tm, __shfl_xor(tm, 2));
      tm = fmaxf(tm, __shfl_xor(tm, 4));
      tm = fmaxf(tm, __shfl_xor(tm, 8));
      float mn = fmaxf(mrow[r], tm);
      float corr = __expf(mrow[r] - mn);
      mrow[r] = mn;
      float rs = 0.f;
      #pragma unroll
      for (int ni = 0; ni < 4; ++ni) {
        float p = __expf(sacc[ni][r] - mn);
        sacc[ni][r] = p;
        rs += p;
      }
      rs += __shfl_xor(rs, 1);
      rs += __shfl_xor(rs, 2);
      rs += __shfl_xor(rs, 4);
      rs += __shfl_xor(rs, 8);
      lrow[r] = lrow[r] * corr + rs;
      #pragma unroll
      for (int ni = 0; ni < 4; ++ni) oacc[ni][r] *= corr;
    }

    // P -> LDS (bf16), per-wave region
    #pragma unroll
    for (int ni = 0; ni < 4; ++ni)
      #pragma unroll
      for (int r = 0; r < 4; ++r)
        Ps[wid][(fgrp * 4 + r) * 72 + ni * 16 + fcol] = f2b(sacc[ni][r]);
    __syncthreads();  // also orders per-wave P write->read

    // O += P @ V   (A = P[q][kp], B = V[kp][d] read from Vt[d][kp])
    #pragma unroll
    for (int kc = 0; kc < 2; ++kc) {
      bf16x8 pa = *(const bf16x8*)&Ps[wid][fcol * 72 + kc * 32 + fgrp * 8];
      #pragma unroll
      for (int ni = 0; ni < 4; ++ni) {
        bf16x8 vb = *(const bf16x8*)&Vt[(ni * 16 + fcol) * 72 + kc * 32 + fgrp * 8];
        oacc[ni] = __builtin_amdgcn_mfma_f32_16x16x32_bf16(pa, vb, oacc[ni], 0, 0, 0);
      }
    }
    __syncthreads();  // before restaging Ks/Vt
  }

  #pragma unroll
  for (int r = 0; r < 4; ++r) {
    float inv = 1.0f / lrow[r];
    int row = qr0 + fgrp * 4 + r;
    #pragma unroll
    for (int ni = 0; ni < 4; ++ni)
      ao[((size_t)(b * S) + row) * H + hh * 64 + ni * 16 + fcol] = f2b(oacc[ni][r] * inv);
  }
}

// ---------------- classifier: softmax(x @ clf_w + clf_b) --------------------
__global__ __launch_bounds__(64) void clf_kernel(
    const float* __restrict__ x, const float* __restrict__ w,
    const float* __restrict__ bvec, float* __restrict__ out) {
  int row = blockIdx.x;
  int lane = threadIdx.x;
  const float* xr = x + (size_t)row * H;
  float p0 = 0.f, p1 = 0.f, p2 = 0.f, p3 = 0.f;
  for (int d = lane; d < H; d += 64) {
    float xv = xr[d];
    p0 += xv * w[d * 4 + 0];
    p1 += xv * w[d * 4 + 1];
    p2 += xv * w[d * 4 + 2];
    p3 += xv * w[d * 4 + 3];
  }
  for (int off = 1; off < 64; off <<= 1) {
    p0 += __shfl_xor(p0, off);
    p1 += __shfl_xor(p1, off);
    p2 += __shfl_xor(p2, off);
    p3 += __shfl_xor(p3, off);
  }
  if (lane == 0) {
    float l0 = p0 + bvec[0], l1 = p1 + bvec[1], l2 = p2 + bvec[2], l3 = p3 + bvec[3];
    float mx = fmaxf(fmaxf(l0, l1), fmaxf(l2, l3));
    float e0 = __expf(l0 - mx), e1 = __expf(l1 - mx), e2 = __expf(l2 - mx), e3 = __expf(l3 - mx);
    float inv = 1.0f / (e0 + e1 + e2 + e3);
    out[row * 4 + 0] = e0 * inv;
    out[row * 4 + 1] = e1 * inv;
    out[row * 4 + 2] = e2 * inv;
    out[row * 4 + 3] = e3 * inv;
  }
}

// ---------------- driver ----------------------------------------------------
extern "C" void kernel_launch(void* const* d_in, const int* in_sizes, int n_in,
                              void* d_out, int out_size, void* d_ws, size_t ws_size,
                              hipStream_t stream) {
  const float* input_ids = (const float*)d_in[0];
  const int*   rand_bl   = (const int*)  d_in[1];
  const float* emb_w = (const float*)d_in[2];
  const float* emb_b = (const float*)d_in[3];
  const float* ln1_g = (const float*)d_in[4];
  const float* ln1_b = (const float*)d_in[5];
  const float* wq = (const float*)d_in[6];
  const float* bq = (const float*)d_in[7];
  const float* wk = (const float*)d_in[8];
  const float* bk = (const float*)d_in[9];
  const float* wv = (const float*)d_in[10];
  const float* bv = (const float*)d_in[11];
  const float* wo = (const float*)d_in[12];
  const float* bo = (const float*)d_in[13];
  const float* ln2_g = (const float*)d_in[14];
  const float* ln2_b = (const float*)d_in[15];
  const float* w1 = (const float*)d_in[16];
  const float* b1 = (const float*)d_in[17];
  const float* w2 = (const float*)d_in[18];
  const float* b2 = (const float*)d_in[19];
  const float* clf_w = (const float*)d_in[20];
  const float* clf_b = (const float*)d_in[21];

  char* p = (char*)d_ws;
  float*    x    = (float*)p;    p += XSZ * 4;
  ushort_t* h    = (ushort_t*)p; p += XSZ * 2;
  ushort_t* qkv  = (ushort_t*)p; p += (size_t)ROWS * QKV_N * 2;
  ushort_t* ao   = (ushort_t*)p; p += XSZ * 2;
  ushort_t* ff   = qkv;  // [ROWS][FF] aliases qkv+ao (dead when FFN runs)
  ushort_t* qkvT = (ushort_t*)p; p += (size_t)L * QKV_N * H * 2;
  ushort_t* woT  = (ushort_t*)p; p += (size_t)L * H * H * 2;
  ushort_t* w1T  = (ushort_t*)p; p += (size_t)L * H * FF * 2;
  ushort_t* w2T  = (ushort_t*)p; p += (size_t)L * FF * H * 2;
  float*    bqkv = (float*)p;    p += (size_t)L * QKV_N * 4;

  // ---- weight prep (every call; deterministic) ----
  tcvt_kernel<<<dim3(H / 32, H / 32, L), 256, 0, stream>>>(
      wq, qkvT + 0 * H * H, H, H, (size_t)H * H, (size_t)QKV_N * H);
  tcvt_kernel<<<dim3(H / 32, H / 32, L), 256, 0, stream>>>(
      wk, qkvT + 1 * H * H, H, H, (size_t)H * H, (size_t)QKV_N * H);
  tcvt_kernel<<<dim3(H / 32, H / 32, L), 256, 0, stream>>>(
      wv, qkvT + 2 * H * H, H, H, (size_t)H * H, (size_t)QKV_N * H);
  tcvt_kernel<<<dim3(H / 32, H / 32, L), 256, 0, stream>>>(
      wo, woT, H, H, (size_t)H * H, (size_t)H * H);
  tcvt_kernel<<<dim3(FF / 32, H / 32, L), 256, 0, stream>>>(
      w1, w1T, H, FF, (size_t)H * FF, (size_t)H * FF);
  tcvt_kernel<<<dim3(H / 32, FF / 32, L), 256, 0, stream>>>(
      w2, w2T, FF, H, (size_t)FF * H, (size_t)FF * H);
  concat_bias_kernel<<<(L * QKV_N + 255) / 256, 256, 0, stream>>>(bq, bk, bv, bqkv);

  embed_kernel<<<(int)((XSZ + 255) / 256), 256, 0, stream>>>(input_ids, emb_w, emb_b, x);

  for (int l = 0; l < L; ++l) {
    ln_kernel<<<ROWS, 256, 0, stream>>>(x, ln1_g + l * H, ln1_b + l * H, h);

    bgemm<0><<<dim3(QKV_N / 128, ROWS / 128), 256, 0, stream>>>(
        h, qkvT + (size_t)l * QKV_N * H, bqkv + l * QKV_N, nullptr,
        nullptr, qkv, ROWS, QKV_N, H);

    attn_mfma<<<dim3(NB, NH, B), 256, 0, stream>>>(qkv, rand_bl, ao);

    bgemm<1><<<dim3(H / 128, ROWS / 128), 256, 0, stream>>>(
        ao, woT + (size_t)l * H * H, bo + l * H, x, x, nullptr, ROWS, H, H);

    ln_kernel<<<ROWS, 256, 0, stream>>>(x, ln2_g + l * H, ln2_b + l * H, h);

    bgemm<2><<<dim3(FF / 128, ROWS / 128), 256, 0, stream>>>(
        h, w1T + (size_t)l * H * FF, b1 + l * FF, nullptr,
        nullptr, ff, ROWS, FF, H);

    bgemm<1><<<dim3(H / 128, ROWS / 128), 256, 0, stream>>>(
        ff, w2T + (size_t)l * FF * H, b2 + l * H, x, x, nullptr, ROWS, H, FF);
  }

  clf_kernel<<<ROWS, 64, 0, stream>>>(x, clf_w, clf_b, (float*)d_out);
}

// Round 3
// 1278.535 us; speedup vs baseline: 6.0436x; 1.0072x over previous
//
#include <hip/hip_runtime.h>
#include <math.h>

// ---------------- problem constants ----------------
constexpr int B  = 2;
constexpr int S  = 4096;
constexpr int H  = 768;
constexpr int NH = 12;
constexpr int FF = 3072;
constexpr int L  = 4;
constexpr int R  = 3;
constexpr int NB = 64;
constexpr int AB = 8;            // 3 window + 2 global + 3 random
constexpr float SCALE = 0.125f;  // 1/sqrt(64)
constexpr int QKV_N = 3 * H;     // 2304

constexpr int ROWS = B * S;                  // 8192
constexpr size_t XSZ = (size_t)B * S * H;    // 6291456

typedef short bf16x8 __attribute__((ext_vector_type(8)));
typedef unsigned short u16x8 __attribute__((ext_vector_type(8)));
typedef float f32x4 __attribute__((ext_vector_type(4)));
typedef unsigned short ushort_t;

// fp32 -> bf16 round-nearest-even
__device__ __forceinline__ ushort_t f2b(float f) {
  union { float f; unsigned u; } c; c.f = f;
  unsigned r = c.u + 0x7fffu + ((c.u >> 16) & 1u);
  return (ushort_t)(r >> 16);
}

__device__ __forceinline__ void gload16(const void* g, void* l) {
  __builtin_amdgcn_global_load_lds(
      (const __attribute__((address_space(1))) unsigned int*)g,
      (__attribute__((address_space(3))) unsigned int*)l, 16, 0, 0);
}

// ---------------- embedding ----------------
__global__ __launch_bounds__(256) void embed_kernel(
    const float* __restrict__ ids, const float* __restrict__ w,
    const float* __restrict__ bvec, float* __restrict__ x) {
  int i = blockIdx.x * 256 + threadIdx.x;
  if (i >= (int)XSZ) return;
  int hc = i % H;
  int bs = i / H;
  float s = bvec[hc];
  #pragma unroll
  for (int j = 0; j < 4; ++j) s += ids[bs * 4 + j] * w[j * H + hc];
  x[i] = s;
}

// ---------------- layernorm: fp32 in -> bf16 out ----------------
__global__ __launch_bounds__(256) void ln_kernel(
    const float* __restrict__ x, const float* __restrict__ g,
    const float* __restrict__ bvec, ushort_t* __restrict__ out) {
  int row = blockIdx.x;
  const float* xr = x + (size_t)row * H;
  int t = threadIdx.x;
  float v0 = xr[t], v1 = xr[t + 256], v2 = xr[t + 512];
  float s  = v0 + v1 + v2;
  float ss = v0 * v0 + v1 * v1 + v2 * v2;
  for (int off = 1; off < 64; off <<= 1) {
    s  += __shfl_xor(s,  off);
    ss += __shfl_xor(ss, off);
  }
  __shared__ float sm[8];
  int w = t >> 6, lane = t & 63;
  if (lane == 0) { sm[w] = s; sm[4 + w] = ss; }
  __syncthreads();
  s  = sm[0] + sm[1] + sm[2] + sm[3];
  ss = sm[4] + sm[5] + sm[6] + sm[7];
  float mean = s * (1.0f / H);
  float var  = ss * (1.0f / H) - mean * mean;
  float rstd = rsqrtf(var + 1e-12f);
  ushort_t* orow = out + (size_t)row * H;
  orow[t]       = f2b((v0 - mean) * rstd * g[t]       + bvec[t]);
  orow[t + 256] = f2b((v1 - mean) * rstd * g[t + 256] + bvec[t + 256]);
  orow[t + 512] = f2b((v2 - mean) * rstd * g[t + 512] + bvec[t + 512]);
}

// ---------------- weight transpose + fp32->bf16 ----------------
__global__ __launch_bounds__(256) void tcvt_kernel(
    const float* __restrict__ in, ushort_t* __restrict__ out,
    int K, int N, size_t inZ, size_t outZ) {
  __shared__ float tile[32][33];
  const float* inz = in + blockIdx.z * inZ;
  ushort_t* outz = out + blockIdx.z * outZ;
  int k0 = blockIdx.y * 32, n0 = blockIdx.x * 32;
  int tx = threadIdx.x & 31, ty = threadIdx.x >> 5;
  #pragma unroll
  for (int i = 0; i < 4; ++i) {
    int kk = ty + i * 8;
    tile[kk][tx] = inz[(size_t)(k0 + kk) * N + n0 + tx];
  }
  __syncthreads();
  #pragma unroll
  for (int i = 0; i < 4; ++i) {
    int nn = ty + i * 8;
    outz[(size_t)(n0 + nn) * K + k0 + tx] = f2b(tile[tx][nn]);
  }
}

__global__ __launch_bounds__(256) void concat_bias_kernel(
    const float* __restrict__ bq, const float* __restrict__ bk,
    const float* __restrict__ bv, float* __restrict__ out) {
  int i = blockIdx.x * 256 + threadIdx.x;
  if (i >= L * QKV_N) return;
  int l = i / QKV_N, c = i % QKV_N;
  float val = (c < H) ? bq[l * H + c] : (c < 2 * H) ? bk[l * H + c - H] : bv[l * H + c - 2 * H];
  out[i] = val;
}

// ============================================================================
// 256x256 8-wave deep-pipelined bf16 MFMA GEMM (T1+T2+T3+T4+T5).
// A[M,K] bf16 row-major, Wt[N,K] bf16 row-major (pre-transposed weights).
// LDS: 2 buffers x 4 units(A0,A1,B0,B1) x 8192 bf16 = 128 KiB.
// Unit = 16KB = 128 "slots" x 64 k. K-chunk XOR swizzle (chunk ^= slot&7),
// applied on the global SOURCE address (linear global_load_lds dest) and on
// the ds_read address (rule 21: both-sides-or-neither).
// Schedule per K-tile (4 phases): stage [A0,B0,B1,A1] of NEXT tile into the
// inactive buffer; per-phase end: s_waitcnt vmcnt(4/4/6/4) lgkmcnt(0) +
// s_barrier. Last tile drains 2 -> 0. Verified by induction: entering any
// tile, exactly {B1,A1} of the next tile are outstanding.
// ============================================================================
#define ENDP(NSTR) \
  asm volatile("s_waitcnt vmcnt(" NSTR ") lgkmcnt(0)" ::: "memory"); \
  __builtin_amdgcn_sched_barrier(0); \
  __builtin_amdgcn_s_barrier(); \
  __builtin_amdgcn_sched_barrier(0);

#define ST_A0(nb) { ushort_t* d = &lds[((nb)*4+0)*8192 + wid*512]; gload16(a00,d); gload16(a01,d+4096); }
#define ST_A1(nb) { ushort_t* d = &lds[((nb)*4+1)*8192 + wid*512]; gload16(a10,d); gload16(a11,d+4096); }
#define ST_B0(nb) { ushort_t* d = &lds[((nb)*4+2)*8192 + wid*512]; gload16(b00,d); gload16(b01,d+4096); }
#define ST_B1(nb) { ushort_t* d = &lds[((nb)*4+3)*8192 + wid*512]; gload16(b10,d); gload16(b11,d+4096); }

#define LOAD_AF(MIP) \
  _Pragma("unroll") for (int i_ = 0; i_ < 4; ++i_) { \
    af[i_][0] = *(const bf16x8*)&lds[bo + aB + (MIP)*8192 + i_*1024 + kq0]; \
    af[i_][1] = *(const bf16x8*)&lds[bo + aB + (MIP)*8192 + i_*1024 + kq1]; }

#define LOAD_B(NI) \
  bfr[NI][0] = *(const bf16x8*)&lds[bo + bB + ((NI)>>1)*8192 + ((NI)&1)*1024 + kq0]; \
  bfr[NI][1] = *(const bf16x8*)&lds[bo + bB + ((NI)>>1)*8192 + ((NI)&1)*1024 + kq1];

#define MFMA_Q(MIP, NIP) \
  __builtin_amdgcn_s_setprio(1); \
  _Pragma("unroll") for (int i_ = 0; i_ < 4; ++i_) \
    _Pragma("unroll") for (int n_ = 0; n_ < 2; ++n_) { \
      acc[(MIP)*4+i_][(NIP)*2+n_] = __builtin_amdgcn_mfma_f32_16x16x32_bf16( \
          af[i_][0], bfr[(NIP)*2+n_][0], acc[(MIP)*4+i_][(NIP)*2+n_], 0, 0, 0); \
      acc[(MIP)*4+i_][(NIP)*2+n_] = __builtin_amdgcn_mfma_f32_16x16x32_bf16( \
          af[i_][1], bfr[(NIP)*2+n_][1], acc[(MIP)*4+i_][(NIP)*2+n_], 0, 0, 0); } \
  __builtin_amdgcn_s_setprio(0);

#define ADV() { a00 += 64; a01 += 64; a10 += 64; a11 += 64; \
                b00 += 64; b01 += 64; b10 += 64; b11 += 64; }

// EPI: 0 = bias -> bf16, 1 = bias + residual -> fp32, 2 = bias + gelu -> bf16
template <int EPI>
__global__ __launch_bounds__(512, 2) void bgemm256(
    const ushort_t* __restrict__ A, const ushort_t* __restrict__ Wt,
    const float* __restrict__ bias, const float* __restrict__ res,
    float* __restrict__ Cf, ushort_t* __restrict__ Cb,
    int M, int N, int K, int ncol) {
  __shared__ ushort_t lds[65536];  // 128 KiB

  // T1: bijective XCD swizzle (m204)
  const int nwg = (int)gridDim.x;
  const int q = nwg >> 3, r0 = nwg & 7;
  const int xcd = (int)blockIdx.x & 7, loc = (int)blockIdx.x >> 3;
  const int swz = (xcd < r0 ? xcd * (q + 1) : r0 * (q + 1) + (xcd - r0) * q) + loc;
  const int bm = (swz / ncol) * 256, bn = (swz % ncol) * 256;

  const int t = threadIdx.x;
  const int wid = t >> 6, lane = t & 63;
  const int fcol = lane & 15, fgrp = lane >> 4;
  const int s7 = fcol & 7;
  const int wm = wid >> 2, wn = wid & 3;

  // staging source addresses (per-lane global gather, pre-swizzled k-chunk)
  const int rho = t >> 3;               // 0..63
  const int chi = t & 7;
  const int swzc = chi ^ (rho & 7);
  const ushort_t* a00 = A + (size_t)(bm + rho      ) * K + swzc * 8;
  const ushort_t* a01 = A + (size_t)(bm + rho + 128) * K + swzc * 8;
  const ushort_t* a10 = A + (size_t)(bm + rho +  64) * K + swzc * 8;
  const ushort_t* a11 = A + (size_t)(bm + rho + 192) * K + swzc * 8;
  const int crow = rho & 31, chi6 = rho >> 5;
  const ushort_t* b00 = Wt + (size_t)(bn + crow      + chi6 * 64)      * K + swzc * 8;
  const ushort_t* b01 = Wt + (size_t)(bn + crow      + (chi6 + 2) * 64) * K + swzc * 8;
  const ushort_t* b10 = Wt + (size_t)(bn + crow + 32 + chi6 * 64)      * K + swzc * 8;
  const ushort_t* b11 = Wt + (size_t)(bn + crow + 32 + (chi6 + 2) * 64) * K + swzc * 8;

  // ds_read bases (element offsets; swizzled k-chunk)
  const int aB  = (wm * 64 + fcol) * 64;
  const int bB  = 16384 + (wn * 32 + fcol) * 64;
  const int kq0 = ((0 * 4 + fgrp) ^ s7) * 8;
  const int kq1 = ((1 * 4 + fgrp) ^ s7) * 8;

  f32x4 acc[8][4] = {};
  bf16x8 af[4][2], bfr[4][2];

  // prologue: stage tile0 into buf0, order [A0,B0,B1,A1]
  ST_A0(0); ST_B0(0); ST_B1(0); ST_A1(0);
  ADV();
  asm volatile("s_waitcnt vmcnt(4)" ::: "memory");
  __builtin_amdgcn_sched_barrier(0);
  __builtin_amdgcn_s_barrier();
  __builtin_amdgcn_sched_barrier(0);

  const int NT = K >> 6;
  for (int tau = 0; tau < NT - 1; ++tau) {
    const int buf = tau & 1, nb = buf ^ 1;
    const int bo = buf * 32768;
    ST_A0(nb); LOAD_AF(0); LOAD_B(0); LOAD_B(1); MFMA_Q(0, 0); ENDP("4");
    ST_B0(nb); LOAD_B(2); LOAD_B(3);             MFMA_Q(0, 1); ENDP("4");
    ST_B1(nb); LOAD_AF(1);                       MFMA_Q(1, 0); ENDP("6");
    ST_A1(nb);                                   MFMA_Q(1, 1); ENDP("4");
    ADV();
  }
  {  // last tile: no stages; drain 2 -> 0
    const int bo = ((NT - 1) & 1) * 32768;
    LOAD_AF(0); LOAD_B(0); LOAD_B(1); MFMA_Q(0, 0); ENDP("2");
    LOAD_B(2); LOAD_B(3);             MFMA_Q(0, 1); ENDP("0");
    LOAD_AF(1);                       MFMA_Q(1, 0);
                                      MFMA_Q(1, 1);
  }

  // epilogue
  #pragma unroll
  for (int mi = 0; mi < 8; ++mi) {
    const int m = bm + wm * 128 + mi * 16 + fgrp * 4;
    #pragma unroll
    for (int ni = 0; ni < 4; ++ni) {
      const int n = bn + wn * 64 + ni * 16 + fcol;
      const float bb = bias[n];
      #pragma unroll
      for (int r = 0; r < 4; ++r) {
        float val = acc[mi][ni][r] + bb;
        if (EPI == 1) {
          Cf[(size_t)(m + r) * N + n] = val + res[(size_t)(m + r) * N + n];
        } else if (EPI == 2) {
          val = 0.5f * val * (1.0f + erff(val * 0.70710678118654752f));
          Cb[(size_t)(m + r) * N + n] = f2b(val);
        } else {
          Cb[(size_t)(m + r) * N + n] = f2b(val);
        }
      }
    }
  }
}

// ---------------- BigBird sparse attention, bf16 MFMA flash-style -----------
__global__ __launch_bounds__(256) void attn_mfma(
    const ushort_t* __restrict__ qkv, const int* __restrict__ rb,
    ushort_t* __restrict__ ao) {
  __shared__ ushort_t Ks[64 * 72];
  __shared__ ushort_t Vt[64 * 72];
  __shared__ ushort_t Ps[4][16 * 72];
  const int n = blockIdx.x, hh = blockIdx.y, b = blockIdx.z;
  const int t = threadIdx.x;
  const int wid = t >> 6, lane = t & 63;
  const int fcol = lane & 15, fgrp = lane >> 4;
  const int qr0 = n * 64 + wid * 16;

  bf16x8 qf[2];
  #pragma unroll
  for (int kc = 0; kc < 2; ++kc)
    qf[kc] = *(const bf16x8*)&qkv[((size_t)(b * S) + qr0 + fcol) * QKV_N + hh * 64 + kc * 32 + fgrp * 8];

  f32x4 oacc[4] = {};
  float mrow[4], lrow[4];
  #pragma unroll
  for (int r = 0; r < 4; ++r) { mrow[r] = -1e30f; lrow[r] = 0.f; }

  const int skp = t >> 3;
  const int sdo = (t & 7) * 8;

  for (int a = 0; a < AB; ++a) {
    int kb;
    if      (a == 0) kb = (n > 0) ? n - 1 : 0;
    else if (a == 1) kb = n;
    else if (a == 2) kb = (n < NB - 1) ? n + 1 : NB - 1;
    else if (a == 3) kb = 0;
    else if (a == 4) kb = NB - 1;
    else             kb = rb[n * R + (a - 5)];

    const ushort_t* kbase = qkv + ((size_t)(b * S) + kb * 64) * QKV_N + H + hh * 64;
    const ushort_t* vbase = qkv + ((size_t)(b * S) + kb * 64) * QKV_N + 2 * H + hh * 64;
    #pragma unroll
    for (int i = 0; i < 2; ++i) {
      int kp = skp + i * 32;
      u16x8 kv = *(const u16x8*)&kbase[(size_t)kp * QKV_N + sdo];
      *(u16x8*)&Ks[kp * 72 + sdo] = kv;
      u16x8 vv = *(const u16x8*)&vbase[(size_t)kp * QKV_N + sdo];
      #pragma unroll
      for (int j = 0; j < 8; ++j) Vt[(sdo + j) * 72 + kp] = vv[j];
    }
    __syncthreads();

    f32x4 sacc[4] = {};
    #pragma unroll
    for (int ni = 0; ni < 4; ++ni)
      #pragma unroll
      for (int kc = 0; kc < 2; ++kc) {
        bf16x8 kf = *(const bf16x8*)&Ks[(ni * 16 + fcol) * 72 + kc * 32 + fgrp * 8];
        sacc[ni] = __builtin_amdgcn_mfma_f32_16x16x32_bf16(qf[kc], kf, sacc[ni], 0, 0, 0);
      }

    #pragma unroll
    for (int ni = 0; ni < 4; ++ni)
      #pragma unroll
      for (int r = 0; r < 4; ++r) sacc[ni][r] *= SCALE;
    #pragma unroll
    for (int r = 0; r < 4; ++r) {
      float tm = fmaxf(fmaxf(sacc[0][r], sacc[1][r]), fmaxf(sacc[2][r], sacc[3][r]));
      tm = fmaxf(tm, __shfl_xor(tm, 1));
      tm = fmaxf(tm, __shfl_xor(tm, 2));
      tm = fmaxf(tm, __shfl_xor(tm, 4));
      tm = fmaxf(tm, __shfl_xor(tm, 8));
      float mn = fmaxf(mrow[r], tm);
      float corr = __expf(mrow[r] - mn);
      mrow[r] = mn;
      float rs = 0.f;
      #pragma unroll
      for (int ni = 0; ni < 4; ++ni) {
        float p = __expf(sacc[ni][r] - mn);
        sacc[ni][r] = p;
        rs += p;
      }
      rs += __shfl_xor(rs, 1);
      rs += __shfl_xor(rs, 2);
      rs += __shfl_xor(rs, 4);
      rs += __shfl_xor(rs, 8);
      lrow[r] = lrow[r] * corr + rs;
      #pragma unroll
      for (int ni = 0; ni < 4; ++ni) oacc[ni][r] *= corr;
    }

    __syncthreads();
    #pragma unroll
    for (int ni = 0; ni < 4; ++ni)
      #pragma unroll
      for (int r = 0; r < 4; ++r)
        Ps[wid][(fgrp * 4 + r) * 72 + ni * 16 + fcol] = f2b(sacc[ni][r]);
    __syncthreads();

    #pragma unroll
    for (int kc = 0; kc < 2; ++kc) {
      bf16x8 pa = *(const bf16x8*)&Ps[wid][fcol * 72 + kc * 32 + fgrp * 8];
      #pragma unroll
      for (int ni = 0; ni < 4; ++ni) {
        bf16x8 vb = *(const bf16x8*)&Vt[(ni * 16 + fcol) * 72 + kc * 32 + fgrp * 8];
        oacc[ni] = __builtin_amdgcn_mfma_f32_16x16x32_bf16(pa, vb, oacc[ni], 0, 0, 0);
      }
    }
    __syncthreads();
  }

  #pragma unroll
  for (int r = 0; r < 4; ++r) {
    float inv = 1.0f / lrow[r];
    int row = qr0 + fgrp * 4 + r;
    #pragma unroll
    for (int ni = 0; ni < 4; ++ni)
      ao[((size_t)(b * S) + row) * H + hh * 64 + ni * 16 + fcol] = f2b(oacc[ni][r] * inv);
  }
}

// ---------------- classifier ----------------
__global__ __launch_bounds__(64) void clf_kernel(
    const float* __restrict__ x, const float* __restrict__ w,
    const float* __restrict__ bvec, float* __restrict__ out) {
  int row = blockIdx.x;
  int lane = threadIdx.x;
  const float* xr = x + (size_t)row * H;
  float p0 = 0.f, p1 = 0.f, p2 = 0.f, p3 = 0.f;
  for (int d = lane; d < H; d += 64) {
    float xv = xr[d];
    p0 += xv * w[d * 4 + 0];
    p1 += xv * w[d * 4 + 1];
    p2 += xv * w[d * 4 + 2];
    p3 += xv * w[d * 4 + 3];
  }
  for (int off = 1; off < 64; off <<= 1) {
    p0 += __shfl_xor(p0, off);
    p1 += __shfl_xor(p1, off);
    p2 += __shfl_xor(p2, off);
    p3 += __shfl_xor(p3, off);
  }
  if (lane == 0) {
    float l0 = p0 + bvec[0], l1 = p1 + bvec[1], l2 = p2 + bvec[2], l3 = p3 + bvec[3];
    float mx = fmaxf(fmaxf(l0, l1), fmaxf(l2, l3));
    float e0 = __expf(l0 - mx), e1 = __expf(l1 - mx), e2 = __expf(l2 - mx), e3 = __expf(l3 - mx);
    float inv = 1.0f / (e0 + e1 + e2 + e3);
    out[row * 4 + 0] = e0 * inv;
    out[row * 4 + 1] = e1 * inv;
    out[row * 4 + 2] = e2 * inv;
    out[row * 4 + 3] = e3 * inv;
  }
}

// ---------------- driver ----------------
extern "C" void kernel_launch(void* const* d_in, const int* in_sizes, int n_in,
                              void* d_out, int out_size, void* d_ws, size_t ws_size,
                              hipStream_t stream) {
  const float* input_ids = (const float*)d_in[0];
  const int*   rand_bl   = (const int*)  d_in[1];
  const float* emb_w = (const float*)d_in[2];
  const float* emb_b = (const float*)d_in[3];
  const float* ln1_g = (const float*)d_in[4];
  const float* ln1_b = (const float*)d_in[5];
  const float* wq = (const float*)d_in[6];
  const float* bq = (const float*)d_in[7];
  const float* wk = (const float*)d_in[8];
  const float* bk = (const float*)d_in[9];
  const float* wv = (const float*)d_in[10];
  const float* bv = (const float*)d_in[11];
  const float* wo = (const float*)d_in[12];
  const float* bo = (const float*)d_in[13];
  const float* ln2_g = (const float*)d_in[14];
  const float* ln2_b = (const float*)d_in[15];
  const float* w1 = (const float*)d_in[16];
  const float* b1 = (const float*)d_in[17];
  const float* w2 = (const float*)d_in[18];
  const float* b2 = (const float*)d_in[19];
  const float* clf_w = (const float*)d_in[20];
  const float* clf_b = (const float*)d_in[21];

  char* p = (char*)d_ws;
  float*    x    = (float*)p;    p += XSZ * 4;
  ushort_t* h    = (ushort_t*)p; p += XSZ * 2;
  ushort_t* qkv  = (ushort_t*)p; p += (size_t)ROWS * QKV_N * 2;
  ushort_t* ao   = (ushort_t*)p; p += XSZ * 2;
  ushort_t* ff   = qkv;  // [ROWS][FF] aliases qkv+ao (dead when FFN runs)
  ushort_t* qkvT = (ushort_t*)p; p += (size_t)L * QKV_N * H * 2;
  ushort_t* woT  = (ushort_t*)p; p += (size_t)L * H * H * 2;
  ushort_t* w1T  = (ushort_t*)p; p += (size_t)L * H * FF * 2;
  ushort_t* w2T  = (ushort_t*)p; p += (size_t)L * FF * H * 2;
  float*    bqkv = (float*)p;    p += (size_t)L * QKV_N * 4;

  // ---- weight prep ----
  tcvt_kernel<<<dim3(H / 32, H / 32, L), 256, 0, stream>>>(
      wq, qkvT + 0 * H * H, H, H, (size_t)H * H, (size_t)QKV_N * H);
  tcvt_kernel<<<dim3(H / 32, H / 32, L), 256, 0, stream>>>(
      wk, qkvT + 1 * H * H, H, H, (size_t)H * H, (size_t)QKV_N * H);
  tcvt_kernel<<<dim3(H / 32, H / 32, L), 256, 0, stream>>>(
      wv, qkvT + 2 * H * H, H, H, (size_t)H * H, (size_t)QKV_N * H);
  tcvt_kernel<<<dim3(H / 32, H / 32, L), 256, 0, stream>>>(
      wo, woT, H, H, (size_t)H * H, (size_t)H * H);
  tcvt_kernel<<<dim3(FF / 32, H / 32, L), 256, 0, stream>>>(
      w1, w1T, H, FF, (size_t)H * FF, (size_t)H * FF);
  tcvt_kernel<<<dim3(H / 32, FF / 32, L), 256, 0, stream>>>(
      w2, w2T, FF, H, (size_t)FF * H, (size_t)FF * H);
  concat_bias_kernel<<<(L * QKV_N + 255) / 256, 256, 0, stream>>>(bq, bk, bv, bqkv);

  embed_kernel<<<(int)((XSZ + 255) / 256), 256, 0, stream>>>(input_ids, emb_w, emb_b, x);

  for (int l = 0; l < L; ++l) {
    ln_kernel<<<ROWS, 256, 0, stream>>>(x, ln1_g + l * H, ln1_b + l * H, h);

    bgemm256<0><<<(ROWS / 256) * (QKV_N / 256), 512, 0, stream>>>(
        h, qkvT + (size_t)l * QKV_N * H, bqkv + l * QKV_N, nullptr,
        nullptr, qkv, ROWS, QKV_N, H, QKV_N / 256);

    attn_mfma<<<dim3(NB, NH, B), 256, 0, stream>>>(qkv, rand_bl, ao);

    bgemm256<1><<<(ROWS / 256) * (H / 256), 512, 0, stream>>>(
        ao, woT + (size_t)l * H * H, bo + l * H, x, x, nullptr, ROWS, H, H, H / 256);

    ln_kernel<<<ROWS, 256, 0, stream>>>(x, ln2_g + l * H, ln2_b + l * H, h);

    bgemm256<2><<<(ROWS / 256) * (FF / 256), 512, 0, stream>>>(
        h, w1T + (size_t)l * H * FF, b1 + l * FF, nullptr,
        nullptr, ff, ROWS, FF, H, FF / 256);

    bgemm256<1><<<(ROWS / 256) * (H / 256), 512, 0, stream>>>(
        ff, w2T + (size_t)l * FF * H, b2 + l * H, x, x, nullptr, ROWS, H, FF, H / 256);
  }

  clf_kernel<<<ROWS, 64, 0, stream>>>(x, clf_w, clf_b, (float*)d_out);
}

// Round 4
// 1124.495 us; speedup vs baseline: 6.8715x; 1.1370x over previous
//
#include <hip/hip_runtime.h>
#include <math.h>

// ---------------- problem constants ----------------
constexpr int B  = 2;
constexpr int S  = 4096;
constexpr int H  = 768;
constexpr int NH = 12;
constexpr int FF = 3072;
constexpr int L  = 4;
constexpr int R  = 3;
constexpr int NB = 64;
constexpr int AB = 8;            // 3 window + 2 global + 3 random
constexpr float SCALE = 0.125f;  // 1/sqrt(64)
constexpr int QKV_N = 3 * H;     // 2304

constexpr int ROWS = B * S;                  // 8192
constexpr size_t XSZ = (size_t)B * S * H;    // 6291456

typedef short bf16x8 __attribute__((ext_vector_type(8)));
typedef unsigned short u16x8 __attribute__((ext_vector_type(8)));
typedef float f32x4 __attribute__((ext_vector_type(4)));
typedef unsigned short ushort_t;

// fp32 -> bf16 round-nearest-even
__device__ __forceinline__ ushort_t f2b(float f) {
  union { float f; unsigned u; } c; c.f = f;
  unsigned r = c.u + 0x7fffu + ((c.u >> 16) & 1u);
  return (ushort_t)(r >> 16);
}

__device__ __forceinline__ void gload16(const void* g, void* l) {
  __builtin_amdgcn_global_load_lds(
      (const __attribute__((address_space(1))) unsigned int*)g,
      (__attribute__((address_space(3))) unsigned int*)l, 16, 0, 0);
}

// ---------------- embedding ----------------
__global__ __launch_bounds__(256) void embed_kernel(
    const float* __restrict__ ids, const float* __restrict__ w,
    const float* __restrict__ bvec, float* __restrict__ x) {
  int i = blockIdx.x * 256 + threadIdx.x;
  if (i >= (int)XSZ) return;
  int hc = i % H;
  int bs = i / H;
  float s = bvec[hc];
  #pragma unroll
  for (int j = 0; j < 4; ++j) s += ids[bs * 4 + j] * w[j * H + hc];
  x[i] = s;
}

// ---------------- layernorm: fp32 in -> bf16 out ----------------
__global__ __launch_bounds__(256) void ln_kernel(
    const float* __restrict__ x, const float* __restrict__ g,
    const float* __restrict__ bvec, ushort_t* __restrict__ out) {
  int row = blockIdx.x;
  const float* xr = x + (size_t)row * H;
  int t = threadIdx.x;
  float v0 = xr[t], v1 = xr[t + 256], v2 = xr[t + 512];
  float s  = v0 + v1 + v2;
  float ss = v0 * v0 + v1 * v1 + v2 * v2;
  for (int off = 1; off < 64; off <<= 1) {
    s  += __shfl_xor(s,  off);
    ss += __shfl_xor(ss, off);
  }
  __shared__ float sm[8];
  int w = t >> 6, lane = t & 63;
  if (lane == 0) { sm[w] = s; sm[4 + w] = ss; }
  __syncthreads();
  s  = sm[0] + sm[1] + sm[2] + sm[3];
  ss = sm[4] + sm[5] + sm[6] + sm[7];
  float mean = s * (1.0f / H);
  float var  = ss * (1.0f / H) - mean * mean;
  float rstd = rsqrtf(var + 1e-12f);
  ushort_t* orow = out + (size_t)row * H;
  orow[t]       = f2b((v0 - mean) * rstd * g[t]       + bvec[t]);
  orow[t + 256] = f2b((v1 - mean) * rstd * g[t + 256] + bvec[t + 256]);
  orow[t + 512] = f2b((v2 - mean) * rstd * g[t + 512] + bvec[t + 512]);
}

// ---------------- weight transpose + fp32->bf16 ----------------
__global__ __launch_bounds__(256) void tcvt_kernel(
    const float* __restrict__ in, ushort_t* __restrict__ out,
    int K, int N, size_t inZ, size_t outZ) {
  __shared__ float tile[32][33];
  const float* inz = in + blockIdx.z * inZ;
  ushort_t* outz = out + blockIdx.z * outZ;
  int k0 = blockIdx.y * 32, n0 = blockIdx.x * 32;
  int tx = threadIdx.x & 31, ty = threadIdx.x >> 5;
  #pragma unroll
  for (int i = 0; i < 4; ++i) {
    int kk = ty + i * 8;
    tile[kk][tx] = inz[(size_t)(k0 + kk) * N + n0 + tx];
  }
  __syncthreads();
  #pragma unroll
  for (int i = 0; i < 4; ++i) {
    int nn = ty + i * 8;
    outz[(size_t)(n0 + nn) * K + k0 + tx] = f2b(tile[tx][nn]);
  }
}

__global__ __launch_bounds__(256) void concat_bias_kernel(
    const float* __restrict__ bq, const float* __restrict__ bk,
    const float* __restrict__ bv, float* __restrict__ out) {
  int i = blockIdx.x * 256 + threadIdx.x;
  if (i >= L * QKV_N) return;
  int l = i / QKV_N, c = i % QKV_N;
  float val = (c < H) ? bq[l * H + c] : (c < 2 * H) ? bk[l * H + c - H] : bv[l * H + c - 2 * H];
  out[i] = val;
}

// ============================================================================
// 128x256 8-wave deep-pipelined bf16 MFMA GEMM (T1+T2+T4+T5).
// Wave grid 2M x 4N -> each wave owns a 64x64 sub-tile (acc[4][4]).
// A[M,K] bf16 row-major, Wt[N,K] bf16 row-major (pre-transposed weights).
// LDS: 2 buffers x (A 128x64 | B 256x64) bf16 = 96 KiB. K-chunk XOR swizzle
// (chunk ^= row&7) applied on the global SOURCE address (linear
// global_load_lds dest) and on the ds_read address (rule 21).
// Per K-tile: stage next tile's 6 loads -> vmcnt(6)+barrier (current tile's
// 6 complete, next's stay in flight) -> 16 ds_read_b128 + 32 MFMA -> barrier.
// Last tile drains vmcnt(0). Grid: (M/128)*(N/256), >=192 blocks all shapes.
// ============================================================================
#define STG(bufO) { \
  ushort_t* d = &lds[(bufO) + wid * 512]; \
  gload16(a0 + kgl, d); \
  gload16(a1 + kgl, d + 4096); \
  gload16(bw0 + kgl, d + 8192); \
  gload16(bw1 + kgl, d + 12288); \
  gload16(bw2 + kgl, d + 16384); \
  gload16(bw3 + kgl, d + 20480); }

#define TILE_COMPUTE(bufO) { \
  _Pragma("unroll") \
  for (int kc = 0; kc < 2; ++kc) { \
    const int ks = kc ? aswz1 : aswz0; \
    bf16x8 af[4], bfr[4]; \
    _Pragma("unroll") \
    for (int i_ = 0; i_ < 4; ++i_) af[i_]  = *(const bf16x8*)&lds[(bufO) + arow + i_ * 1024 + ks]; \
    _Pragma("unroll") \
    for (int i_ = 0; i_ < 4; ++i_) bfr[i_] = *(const bf16x8*)&lds[(bufO) + brow + i_ * 1024 + ks]; \
    __builtin_amdgcn_s_setprio(1); \
    _Pragma("unroll") \
    for (int mi = 0; mi < 4; ++mi) \
      _Pragma("unroll") \
      for (int ni = 0; ni < 4; ++ni) \
        acc[mi][ni] = __builtin_amdgcn_mfma_f32_16x16x32_bf16(af[mi], bfr[ni], acc[mi][ni], 0, 0, 0); \
    __builtin_amdgcn_s_setprio(0); \
  } }

// EPI: 0 = bias -> bf16, 1 = bias + residual -> fp32, 2 = bias + gelu -> bf16
template <int EPI>
__global__ __launch_bounds__(512, 2) void bgemm128(
    const ushort_t* __restrict__ A, const ushort_t* __restrict__ Wt,
    const float* __restrict__ bias, const float* __restrict__ res,
    float* __restrict__ Cf, ushort_t* __restrict__ Cb,
    int M, int N, int K, int ncol) {
  __shared__ ushort_t lds[49152];  // 96 KiB

  // T1: bijective XCD swizzle (m204)
  const int nwg = (int)gridDim.x;
  const int q = nwg >> 3, r0 = nwg & 7;
  const int xcd = (int)blockIdx.x & 7, loc = (int)blockIdx.x >> 3;
  const int swz = (xcd < r0 ? xcd * (q + 1) : r0 * (q + 1) + (xcd - r0) * q) + loc;
  const int bm = (swz / ncol) * 128, bn = (swz % ncol) * 256;

  const int t = threadIdx.x;
  const int wid = t >> 6, lane = t & 63;
  const int fcol = lane & 15, fgrp = lane >> 4;
  const int wm = wid >> 2, wn = wid & 3;

  // staging source addresses (per-lane global gather, pre-swizzled k-chunk)
  const int rho = t >> 3, chi = t & 7;
  const int swzc = chi ^ (rho & 7);
  const ushort_t* a0  = A  + (size_t)(bm + rho       ) * K + swzc * 8;
  const ushort_t* a1  = A  + (size_t)(bm + rho +  64 ) * K + swzc * 8;
  const ushort_t* bw0 = Wt + (size_t)(bn + rho       ) * K + swzc * 8;
  const ushort_t* bw1 = Wt + (size_t)(bn + rho +  64 ) * K + swzc * 8;
  const ushort_t* bw2 = Wt + (size_t)(bn + rho + 128 ) * K + swzc * 8;
  const ushort_t* bw3 = Wt + (size_t)(bn + rho + 192 ) * K + swzc * 8;

  // ds_read bases (element offsets; swizzled k-chunk)
  const int arow  = (wm * 64 + fcol) * 64;          // + mi*1024
  const int brow  = 8192 + (wn * 64 + fcol) * 64;   // + ni*1024
  const int aswz0 = ((0 + fgrp) ^ (fcol & 7)) * 8;  // kc=0
  const int aswz1 = ((4 + fgrp) ^ (fcol & 7)) * 8;  // kc=1

  f32x4 acc[4][4] = {};

  int kgl = 0;
  STG(0);  // tile 0 -> buf 0
  kgl += 64;

  const int NT = K >> 6;
  for (int tau = 0; tau < NT - 1; ++tau) {
    const int cur = (tau & 1) * 24576, nxt = cur ^ 24576;
    STG(nxt);
    kgl += 64;
    asm volatile("s_waitcnt vmcnt(6)" ::: "memory");
    __builtin_amdgcn_sched_barrier(0);
    __builtin_amdgcn_s_barrier();
    __builtin_amdgcn_sched_barrier(0);
    TILE_COMPUTE(cur);
    __builtin_amdgcn_sched_barrier(0);
    __builtin_amdgcn_s_barrier();
    __builtin_amdgcn_sched_barrier(0);
  }
  {  // last tile: drain
    const int cur = ((NT - 1) & 1) * 24576;
    asm volatile("s_waitcnt vmcnt(0)" ::: "memory");
    __builtin_amdgcn_sched_barrier(0);
    __builtin_amdgcn_s_barrier();
    __builtin_amdgcn_sched_barrier(0);
    TILE_COMPUTE(cur);
  }

  // epilogue
  #pragma unroll
  for (int mi = 0; mi < 4; ++mi) {
    const int m = bm + wm * 64 + mi * 16 + fgrp * 4;
    #pragma unroll
    for (int ni = 0; ni < 4; ++ni) {
      const int n = bn + wn * 64 + ni * 16 + fcol;
      const float bb = bias[n];
      #pragma unroll
      for (int r = 0; r < 4; ++r) {
        float val = acc[mi][ni][r] + bb;
        if (EPI == 1) {
          Cf[(size_t)(m + r) * N + n] = val + res[(size_t)(m + r) * N + n];
        } else if (EPI == 2) {
          val = 0.5f * val * (1.0f + erff(val * 0.70710678118654752f));
          Cb[(size_t)(m + r) * N + n] = f2b(val);
        } else {
          Cb[(size_t)(m + r) * N + n] = f2b(val);
        }
      }
    }
  }
}

// ---------------- BigBird sparse attention, bf16 MFMA flash-style -----------
__global__ __launch_bounds__(256) void attn_mfma(
    const ushort_t* __restrict__ qkv, const int* __restrict__ rb,
    ushort_t* __restrict__ ao) {
  __shared__ ushort_t Ks[64 * 72];
  __shared__ ushort_t Vt[64 * 72];
  __shared__ ushort_t Ps[4][16 * 72];
  const int n = blockIdx.x, hh = blockIdx.y, b = blockIdx.z;
  const int t = threadIdx.x;
  const int wid = t >> 6, lane = t & 63;
  const int fcol = lane & 15, fgrp = lane >> 4;
  const int qr0 = n * 64 + wid * 16;

  bf16x8 qf[2];
  #pragma unroll
  for (int kc = 0; kc < 2; ++kc)
    qf[kc] = *(const bf16x8*)&qkv[((size_t)(b * S) + qr0 + fcol) * QKV_N + hh * 64 + kc * 32 + fgrp * 8];

  f32x4 oacc[4] = {};
  float mrow[4], lrow[4];
  #pragma unroll
  for (int r = 0; r < 4; ++r) { mrow[r] = -1e30f; lrow[r] = 0.f; }

  const int skp = t >> 3;
  const int sdo = (t & 7) * 8;

  for (int a = 0; a < AB; ++a) {
    int kb;
    if      (a == 0) kb = (n > 0) ? n - 1 : 0;
    else if (a == 1) kb = n;
    else if (a == 2) kb = (n < NB - 1) ? n + 1 : NB - 1;
    else if (a == 3) kb = 0;
    else if (a == 4) kb = NB - 1;
    else             kb = rb[n * R + (a - 5)];

    const ushort_t* kbase = qkv + ((size_t)(b * S) + kb * 64) * QKV_N + H + hh * 64;
    const ushort_t* vbase = qkv + ((size_t)(b * S) + kb * 64) * QKV_N + 2 * H + hh * 64;
    #pragma unroll
    for (int i = 0; i < 2; ++i) {
      int kp = skp + i * 32;
      u16x8 kv = *(const u16x8*)&kbase[(size_t)kp * QKV_N + sdo];
      *(u16x8*)&Ks[kp * 72 + sdo] = kv;
      u16x8 vv = *(const u16x8*)&vbase[(size_t)kp * QKV_N + sdo];
      #pragma unroll
      for (int j = 0; j < 8; ++j) Vt[(sdo + j) * 72 + kp] = vv[j];
    }
    __syncthreads();

    f32x4 sacc[4] = {};
    #pragma unroll
    for (int ni = 0; ni < 4; ++ni)
      #pragma unroll
      for (int kc = 0; kc < 2; ++kc) {
        bf16x8 kf = *(const bf16x8*)&Ks[(ni * 16 + fcol) * 72 + kc * 32 + fgrp * 8];
        sacc[ni] = __builtin_amdgcn_mfma_f32_16x16x32_bf16(qf[kc], kf, sacc[ni], 0, 0, 0);
      }

    #pragma unroll
    for (int ni = 0; ni < 4; ++ni)
      #pragma unroll
      for (int r = 0; r < 4; ++r) sacc[ni][r] *= SCALE;
    #pragma unroll
    for (int r = 0; r < 4; ++r) {
      float tm = fmaxf(fmaxf(sacc[0][r], sacc[1][r]), fmaxf(sacc[2][r], sacc[3][r]));
      tm = fmaxf(tm, __shfl_xor(tm, 1));
      tm = fmaxf(tm, __shfl_xor(tm, 2));
      tm = fmaxf(tm, __shfl_xor(tm, 4));
      tm = fmaxf(tm, __shfl_xor(tm, 8));
      float mn = fmaxf(mrow[r], tm);
      float corr = __expf(mrow[r] - mn);
      mrow[r] = mn;
      float rs = 0.f;
      #pragma unroll
      for (int ni = 0; ni < 4; ++ni) {
        float p = __expf(sacc[ni][r] - mn);
        sacc[ni][r] = p;
        rs += p;
      }
      rs += __shfl_xor(rs, 1);
      rs += __shfl_xor(rs, 2);
      rs += __shfl_xor(rs, 4);
      rs += __shfl_xor(rs, 8);
      lrow[r] = lrow[r] * corr + rs;
      #pragma unroll
      for (int ni = 0; ni < 4; ++ni) oacc[ni][r] *= corr;
    }

    __syncthreads();
    #pragma unroll
    for (int ni = 0; ni < 4; ++ni)
      #pragma unroll
      for (int r = 0; r < 4; ++r)
        Ps[wid][(fgrp * 4 + r) * 72 + ni * 16 + fcol] = f2b(sacc[ni][r]);
    __syncthreads();

    #pragma unroll
    for (int kc = 0; kc < 2; ++kc) {
      bf16x8 pa = *(const bf16x8*)&Ps[wid][fcol * 72 + kc * 32 + fgrp * 8];
      #pragma unroll
      for (int ni = 0; ni < 4; ++ni) {
        bf16x8 vb = *(const bf16x8*)&Vt[(ni * 16 + fcol) * 72 + kc * 32 + fgrp * 8];
        oacc[ni] = __builtin_amdgcn_mfma_f32_16x16x32_bf16(pa, vb, oacc[ni], 0, 0, 0);
      }
    }
    __syncthreads();
  }

  #pragma unroll
  for (int r = 0; r < 4; ++r) {
    float inv = 1.0f / lrow[r];
    int row = qr0 + fgrp * 4 + r;
    #pragma unroll
    for (int ni = 0; ni < 4; ++ni)
      ao[((size_t)(b * S) + row) * H + hh * 64 + ni * 16 + fcol] = f2b(oacc[ni][r] * inv);
  }
}

// ---------------- classifier ----------------
__global__ __launch_bounds__(64) void clf_kernel(
    const float* __restrict__ x, const float* __restrict__ w,
    const float* __restrict__ bvec, float* __restrict__ out) {
  int row = blockIdx.x;
  int lane = threadIdx.x;
  const float* xr = x + (size_t)row * H;
  float p0 = 0.f, p1 = 0.f, p2 = 0.f, p3 = 0.f;
  for (int d = lane; d < H; d += 64) {
    float xv = xr[d];
    p0 += xv * w[d * 4 + 0];
    p1 += xv * w[d * 4 + 1];
    p2 += xv * w[d * 4 + 2];
    p3 += xv * w[d * 4 + 3];
  }
  for (int off = 1; off < 64; off <<= 1) {
    p0 += __shfl_xor(p0, off);
    p1 += __shfl_xor(p1, off);
    p2 += __shfl_xor(p2, off);
    p3 += __shfl_xor(p3, off);
  }
  if (lane == 0) {
    float l0 = p0 + bvec[0], l1 = p1 + bvec[1], l2 = p2 + bvec[2], l3 = p3 + bvec[3];
    float mx = fmaxf(fmaxf(l0, l1), fmaxf(l2, l3));
    float e0 = __expf(l0 - mx), e1 = __expf(l1 - mx), e2 = __expf(l2 - mx), e3 = __expf(l3 - mx);
    float inv = 1.0f / (e0 + e1 + e2 + e3);
    out[row * 4 + 0] = e0 * inv;
    out[row * 4 + 1] = e1 * inv;
    out[row * 4 + 2] = e2 * inv;
    out[row * 4 + 3] = e3 * inv;
  }
}

// ---------------- driver ----------------
extern "C" void kernel_launch(void* const* d_in, const int* in_sizes, int n_in,
                              void* d_out, int out_size, void* d_ws, size_t ws_size,
                              hipStream_t stream) {
  const float* input_ids = (const float*)d_in[0];
  const int*   rand_bl   = (const int*)  d_in[1];
  const float* emb_w = (const float*)d_in[2];
  const float* emb_b = (const float*)d_in[3];
  const float* ln1_g = (const float*)d_in[4];
  const float* ln1_b = (const float*)d_in[5];
  const float* wq = (const float*)d_in[6];
  const float* bq = (const float*)d_in[7];
  const float* wk = (const float*)d_in[8];
  const float* bk = (const float*)d_in[9];
  const float* wv = (const float*)d_in[10];
  const float* bv = (const float*)d_in[11];
  const float* wo = (const float*)d_in[12];
  const float* bo = (const float*)d_in[13];
  const float* ln2_g = (const float*)d_in[14];
  const float* ln2_b = (const float*)d_in[15];
  const float* w1 = (const float*)d_in[16];
  const float* b1 = (const float*)d_in[17];
  const float* w2 = (const float*)d_in[18];
  const float* b2 = (const float*)d_in[19];
  const float* clf_w = (const float*)d_in[20];
  const float* clf_b = (const float*)d_in[21];

  char* p = (char*)d_ws;
  float*    x    = (float*)p;    p += XSZ * 4;
  ushort_t* h    = (ushort_t*)p; p += XSZ * 2;
  ushort_t* qkv  = (ushort_t*)p; p += (size_t)ROWS * QKV_N * 2;
  ushort_t* ao   = (ushort_t*)p; p += XSZ * 2;
  ushort_t* ff   = qkv;  // [ROWS][FF] aliases qkv+ao (dead when FFN runs)
  ushort_t* qkvT = (ushort_t*)p; p += (size_t)L * QKV_N * H * 2;
  ushort_t* woT  = (ushort_t*)p; p += (size_t)L * H * H * 2;
  ushort_t* w1T  = (ushort_t*)p; p += (size_t)L * H * FF * 2;
  ushort_t* w2T  = (ushort_t*)p; p += (size_t)L * FF * H * 2;
  float*    bqkv = (float*)p;    p += (size_t)L * QKV_N * 4;

  // ---- weight prep ----
  tcvt_kernel<<<dim3(H / 32, H / 32, L), 256, 0, stream>>>(
      wq, qkvT + 0 * H * H, H, H, (size_t)H * H, (size_t)QKV_N * H);
  tcvt_kernel<<<dim3(H / 32, H / 32, L), 256, 0, stream>>>(
      wk, qkvT + 1 * H * H, H, H, (size_t)H * H, (size_t)QKV_N * H);
  tcvt_kernel<<<dim3(H / 32, H / 32, L), 256, 0, stream>>>(
      wv, qkvT + 2 * H * H, H, H, (size_t)H * H, (size_t)QKV_N * H);
  tcvt_kernel<<<dim3(H / 32, H / 32, L), 256, 0, stream>>>(
      wo, woT, H, H, (size_t)H * H, (size_t)H * H);
  tcvt_kernel<<<dim3(FF / 32, H / 32, L), 256, 0, stream>>>(
      w1, w1T, H, FF, (size_t)H * FF, (size_t)H * FF);
  tcvt_kernel<<<dim3(H / 32, FF / 32, L), 256, 0, stream>>>(
      w2, w2T, FF, H, (size_t)FF * H, (size_t)FF * H);
  concat_bias_kernel<<<(L * QKV_N + 255) / 256, 256, 0, stream>>>(bq, bk, bv, bqkv);

  embed_kernel<<<(int)((XSZ + 255) / 256), 256, 0, stream>>>(input_ids, emb_w, emb_b, x);

  for (int l = 0; l < L; ++l) {
    ln_kernel<<<ROWS, 256, 0, stream>>>(x, ln1_g + l * H, ln1_b + l * H, h);

    bgemm128<0><<<(ROWS / 128) * (QKV_N / 256), 512, 0, stream>>>(
        h, qkvT + (size_t)l * QKV_N * H, bqkv + l * QKV_N, nullptr,
        nullptr, qkv, ROWS, QKV_N, H, QKV_N / 256);

    attn_mfma<<<dim3(NB, NH, B), 256, 0, stream>>>(qkv, rand_bl, ao);

    bgemm128<1><<<(ROWS / 128) * (H / 256), 512, 0, stream>>>(
        ao, woT + (size_t)l * H * H, bo + l * H, x, x, nullptr, ROWS, H, H, H / 256);

    ln_kernel<<<ROWS, 256, 0, stream>>>(x, ln2_g + l * H, ln2_b + l * H, h);

    bgemm128<2><<<(ROWS / 128) * (FF / 256), 512, 0, stream>>>(
        h, w1T + (size_t)l * H * FF, b1 + l * FF, nullptr,
        nullptr, ff, ROWS, FF, H, FF / 256);

    bgemm128<1><<<(ROWS / 128) * (H / 256), 512, 0, stream>>>(
        ff, w2T + (size_t)l * FF * H, b2 + l * H, x, x, nullptr, ROWS, H, FF, H / 256);
  }

  clf_kernel<<<ROWS, 64, 0, stream>>>(x, clf_w, clf_b, (float*)d_out);
}